// Round 5
// baseline (309.603 us; speedup 1.0000x reference)
//
#include <hip/hip_runtime.h>
#include <math.h>

#define BSZ 256
#define ENC 128

typedef short s8 __attribute__((ext_vector_type(8)));   // 8 bf16 in 4 VGPRs
typedef float f4 __attribute__((ext_vector_type(4)));   // MFMA 16x16 acc
typedef unsigned short ushort_t;

// Opaque register pin: result of asm can't be rematerialized, so the value
// must stay resident in VGPRs across the whole loop (defeats load sinking).
#define PIN(x) asm volatile("" : "+v"(x))

__device__ __forceinline__ float fexp2f(float x) { return __builtin_amdgcn_exp2f(x); }
__device__ __forceinline__ float frcpf(float x)  { return __builtin_amdgcn_rcpf(x); }
__device__ __forceinline__ float sigf(float x) {
    return frcpf(1.f + fexp2f(x * -1.44269504f));
}
__device__ __forceinline__ float tanh_f(float x) {
    float e = fexp2f(x * 2.88539008f);
    return 1.f - 2.f * frcpf(e + 1.f);
}

__device__ __forceinline__ ushort_t f2b(float f) {
    unsigned u = __float_as_uint(f);
    u = (u + 0x7FFF + ((u >> 16) & 1)) >> 16;   // RNE
    return (ushort_t)u;
}
__device__ __forceinline__ float b2f(ushort_t b) {
    return __uint_as_float(((unsigned)b) << 16);
}

// ---------------------------------------------------------------------------
// Convert emb / Wih / Whh / SW^T to bf16, 4 elems/thread.
// ---------------------------------------------------------------------------
#define EMB_N   6400000          // 50000*128
#define W_N     49152            // 384*128
#define SW_N    16384            // 128*128
#define CVT_N   (EMB_N + 2 * W_N + SW_N)

__global__ __launch_bounds__(256) void cvt_kernel(
    const float* __restrict__ emb, const float* __restrict__ wih,
    const float* __restrict__ whh, const float* __restrict__ sw,
    ushort_t* __restrict__ embb, ushort_t* __restrict__ wihb,
    ushort_t* __restrict__ whhb, ushort_t* __restrict__ swtb)
{
    int i = (blockIdx.x * 256 + threadIdx.x) * 4;
    if (i >= CVT_N) return;
    if (i < EMB_N) {
        float4 v = *(const float4*)(emb + i);
        short4 o; o.x = f2b(v.x); o.y = f2b(v.y); o.z = f2b(v.z); o.w = f2b(v.w);
        *(short4*)(embb + i) = o;
    } else if (i < EMB_N + W_N) {
        int j = i - EMB_N;
        float4 v = *(const float4*)(wih + j);
        short4 o; o.x = f2b(v.x); o.y = f2b(v.y); o.z = f2b(v.z); o.w = f2b(v.w);
        *(short4*)(wihb + j) = o;
    } else if (i < EMB_N + 2 * W_N) {
        int j = i - EMB_N - W_N;
        float4 v = *(const float4*)(whh + j);
        short4 o; o.x = f2b(v.x); o.y = f2b(v.y); o.z = f2b(v.z); o.w = f2b(v.w);
        *(short4*)(whhb + j) = o;
    } else {
        int j = i - EMB_N - 2 * W_N;
        int f = j >> 7, e0 = j & 127;
        short4 o;
        o.x = f2b(sw[(e0 + 0) * 128 + f]);
        o.y = f2b(sw[(e0 + 1) * 128 + f]);
        o.z = f2b(sw[(e0 + 2) * 128 + f]);
        o.w = f2b(sw[(e0 + 3) * 128 + f]);
        *(short4*)(swtb + j) = o;        // SWt[f][e]
    }
}

// ---------------------------------------------------------------------------
// GRU step. Block = 512 thr (8 waves), 128 rows (8 M-tiles). Wave w owns gate
// cols w*16..+15 for all 3 gates; W fragments PINNED in VGPRs for the whole
// block via opaque asm (rounds 3/4 showed the compiler otherwise re-loads
// them every M-tile: VGPR_Count was 44/48, far below the 96+ the frags need).
// Operand-swapped MFMA: D = W_frag x X_frag -> lane holds 4 CONSECUTIVE cols
// (g0 = w*16+quad*4) of row (mt*16 + lane&15): 8B vector h0 loads + h stores.
// ---------------------------------------------------------------------------
template <bool HAS_H0>
__global__ __launch_bounds__(512, 2) void gru_mfma(
    const int* __restrict__ tokens, const ushort_t* __restrict__ embb,
    const ushort_t* __restrict__ wihb, const ushort_t* __restrict__ whhb,
    const float* __restrict__ bih, const float* __restrict__ bhh,
    const ushort_t* __restrict__ h0buf, ushort_t* __restrict__ hbuf,
    int lvl_start)
{
    __shared__ ushort_t xs[128 * 136];   // stride 136: conflict-light b128
    __shared__ ushort_t hs[HAS_H0 ? 128 * 136 : 8];

    const int t = threadIdx.x;
    const int base = blockIdx.x * 128;

    // stage x (and h0): 4 threads per row, 32 shorts each
    {
        int rl = t >> 2, c0 = (t & 3) * 32;
        int row = base + rl;
        int tok = tokens[(lvl_start + (row >> 8)) * BSZ + (row & 255)];
        const ushort_t* src = embb + (size_t)tok * 128 + c0;
        ushort_t* dst = &xs[rl * 136 + c0];
        #pragma unroll
        for (int i = 0; i < 4; ++i) *(s8*)(dst + 8 * i) = *(const s8*)(src + 8 * i);
        if (HAS_H0) {
            const ushort_t* hsrc = h0buf + (size_t)row * 128 + c0;
            ushort_t* hdst = &hs[rl * 136 + c0];
            #pragma unroll
            for (int i = 0; i < 4; ++i) *(s8*)(hdst + 8 * i) = *(const s8*)(hsrc + 8 * i);
        }
    }

    const int lane = t & 63, w = t >> 6;
    const int quad = lane >> 4, l15 = lane & 15;
    const int gA = w * 16 + l15;          // W row (gate col) this lane supplies (A operand)
    const int g0 = w * 16 + quad * 4;     // epilogue col group (D m-index)

    // W fragments in registers, loaded once per block, pinned.
    // A-operand layout: A[m=lane&15][k = s*32 + quad*8 + j]
    s8 bwi[3][4], bwh[3][4];
    #pragma unroll
    for (int gm = 0; gm < 3; ++gm) {
        const ushort_t* wp = wihb + (size_t)(gm * 128 + gA) * 128 + quad * 8;
        #pragma unroll
        for (int s = 0; s < 4; ++s) { bwi[gm][s] = *(const s8*)(wp + 32 * s); PIN(bwi[gm][s]); }
    }
    if (HAS_H0) {
        #pragma unroll
        for (int gm = 0; gm < 3; ++gm) {
            const ushort_t* wp = whhb + (size_t)(gm * 128 + gA) * 128 + quad * 8;
            #pragma unroll
            for (int s = 0; s < 4; ++s) { bwh[gm][s] = *(const s8*)(wp + 32 * s); PIN(bwh[gm][s]); }
        }
    }

    float bR[4], bZ[4], biN[4], bhN[4];
    {
        float4 a = *(const float4*)(bih + g0);
        float4 b = *(const float4*)(bhh + g0);
        bR[0] = a.x + b.x; bR[1] = a.y + b.y; bR[2] = a.z + b.z; bR[3] = a.w + b.w;
        float4 c = *(const float4*)(bih + 128 + g0);
        float4 d = *(const float4*)(bhh + 128 + g0);
        bZ[0] = c.x + d.x; bZ[1] = c.y + d.y; bZ[2] = c.z + d.z; bZ[3] = c.w + d.w;
        float4 e = *(const float4*)(bih + 256 + g0);
        float4 f = *(const float4*)(bhh + 256 + g0);
        biN[0] = e.x; biN[1] = e.y; biN[2] = e.z; biN[3] = e.w;
        bhN[0] = f.x; bhN[1] = f.y; bhN[2] = f.z; bhN[3] = f.w;
    }

    __syncthreads();

    #pragma unroll 1
    for (int mt = 0; mt < 8; ++mt) {
        const int row = mt * 16 + l15;    // B-operand n-index == output row
        s8 ax[4], ah[4];
        {
            const ushort_t* ap = &xs[row * 136 + quad * 8];
            #pragma unroll
            for (int s = 0; s < 4; ++s) ax[s] = *(const s8*)(ap + 32 * s);
            if (HAS_H0) {
                const ushort_t* hp = &hs[row * 136 + quad * 8];
                #pragma unroll
                for (int s = 0; s < 4; ++s) ah[s] = *(const s8*)(hp + 32 * s);
            }
        }

        f4 accR = (f4)0.f, accZ = (f4)0.f, accN = (f4)0.f, accNh = (f4)0.f;
        #pragma unroll
        for (int s = 0; s < 4; ++s) {
            accR = __builtin_amdgcn_mfma_f32_16x16x32_bf16(bwi[0][s], ax[s], accR, 0, 0, 0);
            accZ = __builtin_amdgcn_mfma_f32_16x16x32_bf16(bwi[1][s], ax[s], accZ, 0, 0, 0);
            accN = __builtin_amdgcn_mfma_f32_16x16x32_bf16(bwi[2][s], ax[s], accN, 0, 0, 0);
        }
        if (HAS_H0) {
            #pragma unroll
            for (int s = 0; s < 4; ++s) {
                accR  = __builtin_amdgcn_mfma_f32_16x16x32_bf16(bwh[0][s], ah[s], accR, 0, 0, 0);
                accZ  = __builtin_amdgcn_mfma_f32_16x16x32_bf16(bwh[1][s], ah[s], accZ, 0, 0, 0);
                accNh = __builtin_amdgcn_mfma_f32_16x16x32_bf16(bwh[2][s], ah[s], accNh, 0, 0, 0);
            }
        }

        // epilogue: 4 consecutive cols (g0..g0+3) of `row`
        float h0v[4] = {0.f, 0.f, 0.f, 0.f};
        if (HAS_H0) {
            short4 h04 = *(const short4*)&hs[row * 136 + g0];
            h0v[0] = b2f((ushort_t)h04.x); h0v[1] = b2f((ushort_t)h04.y);
            h0v[2] = b2f((ushort_t)h04.z); h0v[3] = b2f((ushort_t)h04.w);
        }
        ushort_t ov[4];
        #pragma unroll
        for (int r = 0; r < 4; ++r) {
            float rr = sigf(accR[r] + bR[r]);
            float zz = sigf(accZ[r] + bZ[r]);
            float hn = HAS_H0 ? (accNh[r] + bhN[r]) : bhN[r];
            float nn = tanh_f(accN[r] + biN[r] + rr * hn);
            float h = nn + zz * (h0v[r] - nn);
            ov[r] = f2b(h);
        }
        *(short4*)(hbuf + (size_t)(base + row) * 128 + g0) = *(const short4*)ov;
    }
}

// ---------------------------------------------------------------------------
// Attention. Block = 512 thr, 32 parents (128 child rows). Operand-swapped:
// lane holds u for 4 consecutive f-cols of one child row; quad-reduce via
// 2 shfl_xor; cross-wave sum in LDS; softmax over k; vectorized h0 epilogue.
// SW fragments pinned in VGPRs.
// ---------------------------------------------------------------------------
__global__ __launch_bounds__(512, 2) void attn_mfma(
    const ushort_t* __restrict__ hch, ushort_t* __restrict__ h0out,
    const ushort_t* __restrict__ swt, const float* __restrict__ sb,
    const float* __restrict__ cw)
{
    __shared__ ushort_t chs[128 * 136];
    __shared__ float scp[8][128];
    __shared__ float sc[128];
    __shared__ float al[4][32];

    const int t = threadIdx.x;
    const int pbase = blockIdx.x * 32;
    const int pnode = pbase >> 8;
    const int b0 = pbase & 255;

    // stage 128 child rows (k-major: lr = k*32 + bl)
    {
        int lr = t >> 2, c0 = (t & 3) * 32;
        int k = lr >> 5, bl = lr & 31;
        const ushort_t* src = hch + ((size_t)(4 * pnode + k) * BSZ + b0 + bl) * 128 + c0;
        ushort_t* dst = &chs[lr * 136 + c0];
        #pragma unroll
        for (int i = 0; i < 4; ++i) *(s8*)(dst + 8 * i) = *(const s8*)(src + 8 * i);
    }

    const int lane = t & 63, w = t >> 6;
    const int quad = lane >> 4, l15 = lane & 15;
    const int fA = w * 16 + l15;
    const int f0 = w * 16 + quad * 4;

    s8 bsw[4];
    {
        const ushort_t* wp = swt + (size_t)fA * 128 + quad * 8;
        #pragma unroll
        for (int s = 0; s < 4; ++s) { bsw[s] = *(const s8*)(wp + 32 * s); PIN(bsw[s]); }
    }
    float sb4[4], cw4[4];
    {
        float4 a = *(const float4*)(sb + f0);
        float4 b = *(const float4*)(cw + f0);
        sb4[0] = a.x; sb4[1] = a.y; sb4[2] = a.z; sb4[3] = a.w;
        cw4[0] = b.x; cw4[1] = b.y; cw4[2] = b.z; cw4[3] = b.w;
    }
    __syncthreads();

    #pragma unroll 1
    for (int mt = 0; mt < 8; ++mt) {
        const int crow = mt * 16 + l15;
        s8 a[4];
        const ushort_t* ap = &chs[crow * 136 + quad * 8];
        #pragma unroll
        for (int s = 0; s < 4; ++s) a[s] = *(const s8*)(ap + 32 * s);

        f4 acc = (f4)0.f;
        #pragma unroll
        for (int s = 0; s < 4; ++s)
            acc = __builtin_amdgcn_mfma_f32_16x16x32_bf16(bsw[s], a[s], acc, 0, 0, 0);

        float part = 0.f;
        #pragma unroll
        for (int r = 0; r < 4; ++r)
            part += tanh_f(acc[r] + sb4[r]) * cw4[r];
        part += __shfl_xor(part, 16);
        part += __shfl_xor(part, 32);
        if (quad == 0) scp[w][mt * 16 + l15] = part;
    }
    __syncthreads();

    if (t < 128) {
        float s = 0.f;
        #pragma unroll
        for (int ww = 0; ww < 8; ++ww) s += scp[ww][t];
        sc[t] = tanh_f(s);
    }
    __syncthreads();

    if (t < 32) {
        float s0 = sc[t], s1 = sc[32 + t], s2 = sc[64 + t], s3 = sc[96 + t];
        float m = fmaxf(fmaxf(s0, s1), fmaxf(s2, s3));
        float e0 = fexp2f((s0 - m) * 1.44269504f), e1 = fexp2f((s1 - m) * 1.44269504f);
        float e2 = fexp2f((s2 - m) * 1.44269504f), e3 = fexp2f((s3 - m) * 1.44269504f);
        float inv = frcpf(e0 + e1 + e2 + e3);
        al[0][t] = e0 * inv; al[1][t] = e1 * inv; al[2][t] = e2 * inv; al[3][t] = e3 * inv;
    }
    __syncthreads();

    {
        int bl = t >> 4, e0 = (t & 15) * 8;
        float a0 = al[0][bl], a1 = al[1][bl], a2 = al[2][bl], a3 = al[3][bl];
        s8 c0v = *(const s8*)&chs[(0 * 32 + bl) * 136 + e0];
        s8 c1v = *(const s8*)&chs[(1 * 32 + bl) * 136 + e0];
        s8 c2v = *(const s8*)&chs[(2 * 32 + bl) * 136 + e0];
        s8 c3v = *(const s8*)&chs[(3 * 32 + bl) * 136 + e0];
        ushort_t ov[8];
        #pragma unroll
        for (int j = 0; j < 8; ++j) {
            float v = a0 * b2f((ushort_t)c0v[j]) + a1 * b2f((ushort_t)c1v[j])
                    + a2 * b2f((ushort_t)c2v[j]) + a3 * b2f((ushort_t)c3v[j]);
            ov[j] = f2b(v);
        }
        *(s8*)(h0out + (size_t)(pbase + bl) * 128 + e0) = *(const s8*)ov;
    }
}

// ---------------------------------------------------------------------------
// Partial max over ALL 1365 nodes (hall buffer): grid (16, CHUNKS).
// ---------------------------------------------------------------------------
#define MAX_CHUNKS 16
__global__ __launch_bounds__(256) void max_part(
    const ushort_t* __restrict__ h, int nodes, float* __restrict__ pmax)
{
    int e0 = (blockIdx.x * 256 + threadIdx.x) * 8;    // 0..32760
    int y = blockIdx.y;
    int cn = (nodes + MAX_CHUNKS - 1) / MAX_CHUNKS;
    int n0 = y * cn, n1 = min(nodes, n0 + cn);
    float v[8];
    #pragma unroll
    for (int j = 0; j < 8; ++j) v[j] = -INFINITY;
    for (int n = n0; n < n1; ++n) {
        s8 hv = *(const s8*)(h + (size_t)n * 32768 + e0);
        #pragma unroll
        for (int j = 0; j < 8; ++j) v[j] = fmaxf(v[j], b2f((ushort_t)hv[j]));
    }
    float* p = pmax + (size_t)y * 32768 + e0;
    #pragma unroll
    for (int j = 0; j < 8; ++j) p[j] = v[j];
}

__global__ __launch_bounds__(256) void final_max(
    const float* __restrict__ pmax, float* __restrict__ out)
{
    int e = blockIdx.x * 256 + threadIdx.x;
    float v = -INFINITY;
    #pragma unroll
    for (int r = 0; r < MAX_CHUNKS; ++r)
        v = fmaxf(v, pmax[(size_t)r * 32768 + e]);
    out[e] = v;
}

extern "C" void kernel_launch(void* const* d_in, const int* in_sizes, int n_in,
                              void* d_out, int out_size, void* d_ws, size_t ws_size,
                              hipStream_t stream)
{
    const int*   tokens = (const int*)d_in[0];
    const float* emb    = (const float*)d_in[1];
    const float* Wih    = (const float*)d_in[2];
    const float* Whh    = (const float*)d_in[3];
    const float* bih    = (const float*)d_in[4];
    const float* bhh    = (const float*)d_in[5];
    const float* SW     = (const float*)d_in[6];
    const float* sb     = (const float*)d_in[7];
    const float* cw     = (const float*)d_in[8];
    float* out = (float*)d_out;

    // ws layout: emb 12.8MB | W 0.2MB | hall (all levels) 89.4MB | h0 16.8MB | pmax 2MB
    ushort_t* embb = (ushort_t*)d_ws;
    ushort_t* wihb = embb + (size_t)EMB_N;
    ushort_t* whhb = wihb + W_N;
    ushort_t* swtb = whhb + W_N;
    ushort_t* hall = swtb + SW_N;
    ushort_t* h0b  = hall + (size_t)1365 * 32768;
    float*    pmax = (float*)(h0b + (size_t)65536 * 128);

    const int starts[6] = {0, 1, 5, 21, 85, 341};
    const int nsz[6]    = {1, 4, 16, 64, 256, 1024};

    cvt_kernel<<<(CVT_N / 4 + 255) / 256, 256, 0, stream>>>(
        emb, Wih, Whh, SW, embb, wihb, whhb, swtb);

    // leaf level d=5 (h0 = 0)
    {
        int rows = nsz[5] * BSZ;
        gru_mfma<false><<<rows / 128, 512, 0, stream>>>(
            tokens, embb, wihb, whhb, bih, bhh, nullptr,
            hall + (size_t)starts[5] * 32768, starts[5]);
    }
    // internal levels d=4..0
    for (int d = 4; d >= 0; --d) {
        int rows = nsz[d] * BSZ;
        attn_mfma<<<rows / 32, 512, 0, stream>>>(
            hall + (size_t)starts[d + 1] * 32768, h0b, swtb, sb, cw);
        gru_mfma<true><<<rows / 128, 512, 0, stream>>>(
            tokens, embb, wihb, whhb, bih, bhh, h0b,
            hall + (size_t)starts[d] * 32768, starts[d]);
    }
    max_part<<<dim3(16, MAX_CHUNKS), 256, 0, stream>>>(hall, 1365, pmax);
    final_max<<<128, 256, 0, stream>>>(pmax, out);
}